// Round 6
// baseline (354.767 us; speedup 1.0000x reference)
//
#include <hip/hip_runtime.h>
#include <math.h>

#define B_ 2
#define S_ 8
#define N_ 150
#define H_ 128
#define F_ 40
#define EF_ 82
#define NP_ 160            // N padded to 10 j-tiles of 16
#define MPQ 136            // mbuf row pitch in bf16 elems (128 + 8 pad)

typedef __attribute__((ext_vector_type(8))) short short8;
typedef __attribute__((ext_vector_type(4))) float float4v;

__device__ __forceinline__ float silu_f(float v) {
    return v * __builtin_amdgcn_rcpf(1.0f + __expf(-v));
}

// fp32 -> bf16 bits, round-to-nearest-even (identical across rounds)
__device__ __forceinline__ unsigned short f2bf(float f) {
    unsigned u = __builtin_bit_cast(unsigned, f);
    return (unsigned short)((u + 0x7fffu + ((u >> 16) & 1u)) >> 16);
}

// ============ prep kernel ============
// blocks 0..95    : pack 3 layers' We2 -> bf16 transposed [c][k]
// blocks 96..111  : restore absolute coords (one bs each)
// blocks 112..138 : transpose Wh (2 layers) -> WhT[f][k] fp32
// blocks 139..213 : node0 one-hot h0 + Af/Bf via 3-row gather (4 nodes/block)
__global__ __launch_bounds__(512) void prep_kernel(
    const float* __restrict__ x, const float* __restrict__ R,
    const int* __restrict__ pep, const int* __restrict__ labels,
    const int* __restrict__ aapos,
    const float* __restrict__ We1, const float* __restrict__ be1,
    const float* __restrict__ tp, const float* __restrict__ wt,
    const float* __restrict__ wbt,
    const float* __restrict__ w2a, const float* __restrict__ w2b,
    const float* __restrict__ w2c,
    const float* __restrict__ Wh,          // [2][168][40]
    unsigned short* __restrict__ we2t,
    float* __restrict__ WhT,               // [2][40][168]
    float* __restrict__ xa, float* __restrict__ x0,
    float* __restrict__ h0, float* __restrict__ Af, float* __restrict__ Bf)
{
    int blk = blockIdx.x;
    int tid = threadIdx.x;
    if (blk < 96) {
        int e = blk * 512 + tid;                 // < 49152
        int l = e >> 14, idx = e & 16383;
        int k = idx >> 7, c = idx & 127;
        const float* src = (l == 0) ? w2a : (l == 1) ? w2b : w2c;
        we2t[l * 16384 + c * H_ + k] = f2bf(src[idx]);
    } else if (blk < 112) {
        int bs = blk - 96;
        int b = bs / S_;
        __shared__ float xL[N_ * 3];
        if (tid < N_ * 3) xL[tid] = x[bs * N_ * 3 + tid];
        __syncthreads();
        if (tid < N_ * 3) {
            int i = tid / 3, d = tid % 3;
            const float* Rrow = R + (b * N_ + i) * N_;
            float acc = 0.0f;
#pragma unroll 5
            for (int j = 0; j < N_; j++) acc += xL[j * 3 + d] * Rrow[j];
            xa[bs * N_ * 3 + tid] = acc;
            x0[bs * N_ * 3 + tid] = acc;
        }
    } else if (blk < 139) {
        int e = (blk - 112) * 512 + tid;         // < 13824
        if (e < 2 * (F_ + H_) * F_) {            // 13440
            int l = e / 6720, r = e % 6720;
            int f = r / 168, k = r % 168;
            WhT[e] = Wh[l * 6720 + k * F_ + f];
        }
    } else {
        int sub = tid >> 7, c = tid & 127;
        int bi = (blk - 139) * 4 + sub;          // < 300
        int b = bi / N_, i = bi % N_;
        int al = labels[bi];
        int ap = aapos[bi];                       // 1..15
        int aa = pep[b * 15 + ap - 1];
        int r0 = al, r1 = 5 + aa, r2 = 25 + ap - 1;
        float fa = We1[r0 * H_ + c] + We1[r1 * H_ + c] + We1[r2 * H_ + c]
                 + be1[c] + tp[b] * wt[c] + wbt[c];
        float fb = We1[(F_ + r0) * H_ + c] + We1[(F_ + r1) * H_ + c]
                 + We1[(F_ + r2) * H_ + c];
        float hv = 0.0f;
        if (c < F_) hv = (c == r0 || c == r1 || c == r2) ? 1.0f : 0.0f;
        for (int s = 0; s < S_; s++) {
            int n = (b * S_ + s) * N_ + i;
            Af[n * H_ + c] = fa;
            Bf[n * H_ + c] = fb;
            if (c < F_) h0[n * F_ + c] = hv;
        }
    }
}

// ============ edge kernel: block per (bs,i); software-pipelined; fused node ====
// NOTE: Af_out/Bf_out MUST NOT alias Afeat/Bfeat (cross-block WAR race — R4 bug).
// Loop order: B-loads issued at TOP of iter, consumed at BOTTOM (m-compute) —
// the whole load-to-use window (MFMA + epilogue silus ~400cy) sits inside one
// barrier interval, so the vmcnt(0) drain at s_barrier costs nothing.
__global__ __launch_bounds__(256, 4) void edge_kernel(
    const float* __restrict__ x_in,    // [BS*N,3]
    const float* __restrict__ Afeat,   // [BS*N,128]
    const float* __restrict__ Bfeat,   // [BS*N,128]
    const float* __restrict__ We1,     // current layer [82,128]: rows 80/81
    const unsigned short* __restrict__ we2t,  // [128c][128k] bf16
    const float* __restrict__ be2,
    const float* __restrict__ Wc,
    const float* __restrict__ bcp,
    const float* __restrict__ bond,
    const float* __restrict__ emask,
    // fused node (next layer) params (unused in final mode):
    const float* __restrict__ h_in,    // [BS*N,40]
    const float* __restrict__ WhT,     // [40][168] transposed
    const float* __restrict__ bh,      // [40]
    const float* __restrict__ We1n,    // next layer [82,128]
    const float* __restrict__ be1n,
    const float* __restrict__ tpn,
    const float* __restrict__ wtn,
    const float* __restrict__ wbtn,
    int has_t_next,
    // final mode:
    const float* __restrict__ x0v,
    const float* __restrict__ amask,
    int final_mode,
    float* __restrict__ x_out,
    float* __restrict__ h_out,         // may be null (dead store elision)
    float* __restrict__ Af_out,
    float* __restrict__ Bf_out)
{
    __shared__ __align__(16) short mbuf[2][16 * MPQ];   // 8704 B
    __shared__ float4 diffE[NP_];                        // d0,d1,d2,em
    __shared__ float2 dbL[NP_];                          // dist, bond
    __shared__ float DsumL[3];
    __shared__ float wpart[4][3];
    __shared__ float cat[F_ + H_];                       // h(40) + agg(128)
    __shared__ float part[160];
    __shared__ float hnewL[F_];

    int blk = blockIdx.x;
    int i = blk % N_, bs = blk / N_, b = bs / S_;
    int tid = threadIdx.x;
    int node = bs * N_ + i;
    int lane = tid & 63, w = tid >> 6;
    int qd = lane >> 4, l15 = lane & 15;
    int rowLoc = tid >> 4, c0 = (tid & 15) * 8;

    float xi0 = x_in[node * 3 + 0];
    float xi1 = x_in[node * 3 + 1];
    float xi2 = x_in[node * 3 + 2];

    // ---- stage per-j scalars ----
    if (tid < NP_) {
        int j = tid;
        float xj0 = xi0, xj1 = xi1, xj2 = xi2, bnd = 0.0f, emv = 0.0f;
        if (j < N_) {
            int nj = bs * N_ + j;
            xj0 = x_in[nj * 3 + 0];
            xj1 = x_in[nj * 3 + 1];
            xj2 = x_in[nj * 3 + 2];
            int eij = (b * N_ + i) * N_ + j;
            bnd = bond[eij];
            emv = (j == i) ? 0.0f : emask[eij];
        }
        float d0 = xi0 - xj0, d1 = xi1 - xj1, d2 = xi2 - xj2;
        diffE[j] = make_float4(d0, d1, d2, emv);
        dbL[j] = make_float2(sqrtf(d0 * d0 + d1 * d1 + d2 * d2 + 1e-12f), bnd);
    }

    // ---- hoisted m-compute constants: this thread's 8 channels ----
    float afr[8], w80r[8], w81r[8];
    {
        float4 t0 = *(const float4*)&Afeat[node * H_ + c0];
        float4 t1 = *(const float4*)&Afeat[node * H_ + c0 + 4];
        afr[0]=t0.x; afr[1]=t0.y; afr[2]=t0.z; afr[3]=t0.w;
        afr[4]=t1.x; afr[5]=t1.y; afr[6]=t1.z; afr[7]=t1.w;
        t0 = *(const float4*)&We1[80 * H_ + c0];
        t1 = *(const float4*)&We1[80 * H_ + c0 + 4];
        w80r[0]=t0.x; w80r[1]=t0.y; w80r[2]=t0.z; w80r[3]=t0.w;
        w80r[4]=t1.x; w80r[5]=t1.y; w80r[6]=t1.z; w80r[7]=t1.w;
        t0 = *(const float4*)&We1[81 * H_ + c0];
        t1 = *(const float4*)&We1[81 * H_ + c0 + 4];
        w81r[0]=t0.x; w81r[1]=t0.y; w81r[2]=t0.z; w81r[3]=t0.w;
        w81r[4]=t1.x; w81r[5]=t1.y; w81r[6]=t1.z; w81r[7]=t1.w;
    }

    // ---- epilogue constants + hoisted We2 b-frags ----
    int ctb = w * 2;
    float b2r0 = be2[ctb * 16 + l15],  b2r1 = be2[ctb * 16 + 16 + l15];
    float wc0  = Wc[ctb * 16 + l15],   wc1  = Wc[ctb * 16 + 16 + l15];
    const unsigned short* bb0 = we2t + (ctb * 16 + l15) * H_ + qd * 8;
    const unsigned short* bb1 = bb0 + 16 * H_;
    short8 bf00 = *(const short8*)(bb0 +  0);
    short8 bf01 = *(const short8*)(bb0 + 32);
    short8 bf02 = *(const short8*)(bb0 + 64);
    short8 bf03 = *(const short8*)(bb0 + 96);
    short8 bf10 = *(const short8*)(bb1 +  0);
    short8 bf11 = *(const short8*)(bb1 + 32);
    short8 bf12 = *(const short8*)(bb1 + 64);
    short8 bf13 = *(const short8*)(bb1 + 96);

    __syncthreads();

    // ---- Dsum[d] = sum_j diff (wave 0) ----
    if (w == 0) {
        float p0 = 0, p1 = 0, p2 = 0;
        for (int j = lane; j < NP_; j += 64) {
            float4 d = diffE[j];
            p0 += d.x; p1 += d.y; p2 += d.z;
        }
        for (int s = 1; s < 64; s <<= 1) {
            p0 += __shfl_xor(p0, s, 64);
            p1 += __shfl_xor(p1, s, 64);
            p2 += __shfl_xor(p2, s, 64);
        }
        if (lane == 0) { DsumL[0] = p0; DsumL[1] = p1; DsumL[2] = p2; }
    }

    // ---- prologue: compute m(tile 0) ----
    {
        const float* bp = &Bfeat[(bs * N_ + rowLoc) * H_ + c0];   // rowLoc < 150
        float4 b0 = *(const float4*)bp;
        float4 b1 = *(const float4*)(bp + 4);
        float br[8] = {b0.x, b0.y, b0.z, b0.w, b1.x, b1.y, b1.z, b1.w};
        float2 db = dbL[rowLoc];
        short8 pkv;
#pragma unroll
        for (int u = 0; u < 8; u++)
            pkv[u] = (short)f2bf(silu_f(afr[u] + br[u] + db.x * w80r[u] + db.y * w81r[u]));
        *(short8*)&mbuf[0][rowLoc * MPQ + c0] = pkv;
    }
    __syncthreads();

    float aggP0 = 0, aggP1 = 0;
    float SP00 = 0, SP01 = 0, SP02 = 0, SP10 = 0, SP11 = 0, SP12 = 0;

#pragma unroll 2
    for (int jt = 0; jt < 10; jt++) {
        short* mb = mbuf[jt & 1];

        // TOP: issue next tile's Bfeat loads (consumed at bottom of this iter)
        int jr = jt * 16 + 16 + rowLoc;
        float4 nb0 = {0,0,0,0}, nb1 = {0,0,0,0};
        if (jt < 9 && jr < N_) {
            const float* bp = &Bfeat[(bs * N_ + jr) * H_ + c0];
            nb0 = *(const float4*)bp;
            nb1 = *(const float4*)(bp + 4);
        }

        // a-frag LDS reads
        const short* arow = &mb[l15 * MPQ + qd * 8];
        short8 a0 = *(const short8*)(arow +  0);
        short8 a1 = *(const short8*)(arow + 32);
        short8 a2 = *(const short8*)(arow + 64);
        short8 a3 = *(const short8*)(arow + 96);

        // MFMA [16j x 128k] @ [128k x 32c per wave]
        float4v acc0 = {0, 0, 0, 0}, acc1 = {0, 0, 0, 0};
        acc0 = __builtin_amdgcn_mfma_f32_16x16x32_bf16(a0, bf00, acc0, 0, 0, 0);
        acc1 = __builtin_amdgcn_mfma_f32_16x16x32_bf16(a0, bf10, acc1, 0, 0, 0);
        acc0 = __builtin_amdgcn_mfma_f32_16x16x32_bf16(a1, bf01, acc0, 0, 0, 0);
        acc1 = __builtin_amdgcn_mfma_f32_16x16x32_bf16(a1, bf11, acc1, 0, 0, 0);
        acc0 = __builtin_amdgcn_mfma_f32_16x16x32_bf16(a2, bf02, acc0, 0, 0, 0);
        acc1 = __builtin_amdgcn_mfma_f32_16x16x32_bf16(a2, bf12, acc1, 0, 0, 0);
        acc0 = __builtin_amdgcn_mfma_f32_16x16x32_bf16(a3, bf03, acc0, 0, 0, 0);
        acc1 = __builtin_amdgcn_mfma_f32_16x16x32_bf16(a3, bf13, acc1, 0, 0, 0);

        // epilogue(jt): silu, mask, reduce over rows (~350cy — load-hiding window)
#pragma unroll
        for (int r = 0; r < 4; r++) {
            int j = jt * 16 + qd * 4 + r;
            float4 de = diffE[j];
            float mv0 = silu_f(acc0[r] + b2r0) * de.w;
            float mv1 = silu_f(acc1[r] + b2r1) * de.w;
            aggP0 += mv0; aggP1 += mv1;
            SP00 += de.x * mv0; SP01 += de.y * mv0; SP02 += de.z * mv0;
            SP10 += de.x * mv1; SP11 += de.y * mv1; SP12 += de.z * mv1;
        }

        // BOTTOM: m-compute(jt+1) — consumes the loads issued at top
        if (jt < 9) {
            short8 pkv;
            if (jr < N_) {
                float br[8] = {nb0.x, nb0.y, nb0.z, nb0.w, nb1.x, nb1.y, nb1.z, nb1.w};
                float2 db = dbL[jr];
#pragma unroll
                for (int u = 0; u < 8; u++)
                    pkv[u] = (short)f2bf(silu_f(afr[u] + br[u] + db.x * w80r[u] + db.y * w81r[u]));
            } else {
#pragma unroll
                for (int u = 0; u < 8; u++) pkv[u] = 0;
            }
            *(short8*)&mbuf[(jt + 1) & 1][rowLoc * MPQ + c0] = pkv;
        }
        __syncthreads();
    }

    // ---- cross-quad reduction (rows live in quads) ----
#define QR_(v) { v += __shfl_xor(v, 16, 64); v += __shfl_xor(v, 32, 64); }
    QR_(aggP0) QR_(aggP1)
    QR_(SP00) QR_(SP01) QR_(SP02)
    QR_(SP10) QR_(SP11) QR_(SP12)
#undef QR_

    // deferred cw: x_d += (sum_c Wc[c]*S[d][c] + bc*Dsum[d]) / (N-1)
    float p0 = wc0 * SP00 + wc1 * SP10;
    float p1 = wc0 * SP01 + wc1 * SP11;
    float p2 = wc0 * SP02 + wc1 * SP12;
    for (int s = 1; s < 16; s <<= 1) {
        p0 += __shfl_xor(p0, s, 64);
        p1 += __shfl_xor(p1, s, 64);
        p2 += __shfl_xor(p2, s, 64);
    }
    if (lane == 0) { wpart[w][0] = p0; wpart[w][1] = p1; wpart[w][2] = p2; }
    if (!final_mode) {
        if (qd == 0) {
            cat[F_ + ctb * 16 + l15]      = aggP0;      // agg -> cat[40..167]
            cat[F_ + ctb * 16 + 16 + l15] = aggP1;
        }
        if (tid < F_) cat[tid] = h_in[node * F_ + tid];
    }
    __syncthreads();
    if (tid < 3) {
        float tot = wpart[0][tid] + wpart[1][tid] + wpart[2][tid] + wpart[3][tid]
                  + bcp[0] * DsumL[tid];
        float xn = x_in[node * 3 + tid] + tot * (1.0f / (float)(N_ - 1));
        if (final_mode)
            x_out[node * 3 + tid] = (xn - x0v[node * 3 + tid]) * amask[b * N_ + i];
        else
            x_out[node * 3 + tid] = xn;
    }
    if (final_mode) return;

    // ---- fused node: h_out = silu([h,agg]@Wh+bh); next-layer Af/Bf ----
    // WhT rows are consecutive in k -> vectorized loads, no strided stalls.
    if (tid < 160) {
        int f = tid >> 2, ks = tid & 3;          // 4-way k-split of 168 = 4*42
        int k0 = ks * 42;
        const float* wr = WhT + f * (F_ + H_);
        float p = 0.0f;
#pragma unroll 6
        for (int k = k0; k < k0 + 42; k++) p += cat[k] * wr[k];
        part[tid] = p;
    }
    __syncthreads();
    if (tid < F_) {
        float hv = silu_f(part[tid * 4] + part[tid * 4 + 1] + part[tid * 4 + 2]
                        + part[tid * 4 + 3] + bh[tid]);
        hnewL[tid] = hv;
        if (h_out) h_out[node * F_ + tid] = hv;
    }
    __syncthreads();
    {
        int c = tid & 127, grp = tid >> 7;
        float acc = 0.0f;
        if (grp == 0) {
            acc = be1n[c];
            if (has_t_next) acc += tpn[b] * wtn[c] + wbtn[c];
        }
        const float* Wp = We1n + grp * F_ * H_ + c;
#pragma unroll 8
        for (int k = 0; k < F_; k++) acc += hnewL[k] * Wp[k * H_];
        if (grp == 0) Af_out[node * H_ + c] = acc;
        else          Bf_out[node * H_ + c] = acc;
    }
}

extern "C" void kernel_launch(void* const* d_in, const int* in_sizes, int n_in,
                              void* d_out, int out_size, void* d_ws, size_t ws_size,
                              hipStream_t stream) {
    const float* t     = (const float*)d_in[0];
    const float* x     = (const float*)d_in[1];
    const int*   pep   = (const int*)d_in[2];
    const int*   labels= (const int*)d_in[3];
    const int*   aapos = (const int*)d_in[4];
    const float* bond  = (const float*)d_in[5];
    const float* em    = (const float*)d_in[6];
    const float* amask = (const float*)d_in[7];
    const float* R     = (const float*)d_in[8];
    const float* W_e1  = (const float*)d_in[9];
    const float* b_e1  = (const float*)d_in[10];
    const float* W_e2  = (const float*)d_in[11];
    const float* b_e2  = (const float*)d_in[12];
    const float* W_c   = (const float*)d_in[13];
    const float* b_c   = (const float*)d_in[14];
    const float* W_h   = (const float*)d_in[15];
    const float* b_h   = (const float*)d_in[16];
    const float* w_t   = (const float*)d_in[17];
    const float* w_b_t = (const float*)d_in[18];
    const float* tW_e1 = (const float*)d_in[19];
    const float* tb_e1 = (const float*)d_in[20];
    const float* tW_e2 = (const float*)d_in[21];
    const float* tb_e2 = (const float*)d_in[22];
    const float* tW_c  = (const float*)d_in[23];
    const float* tb_c  = (const float*)d_in[24];
    float* out = (float*)d_out;

    float* ws = (float*)d_ws;
    unsigned short* we2t = (unsigned short*)ws;   // 49152 shorts = 24576 float slots
    float* WhT = ws + 24576;         // 13440  (2 layers x [40][168])
    float* x0  = WhT + 13440;        // 7200
    float* xA  = x0 + 7200;          // 7200
    float* xB  = xA + 7200;          // 7200
    float* hA  = xB + 7200;          // 96000
    float* hB  = hA + 96000;         // 96000
    float* AfA = hB + 96000;         // 307200  (ping)
    float* BfA = AfA + 307200;       // 307200
    float* AfB = BfA + 307200;       // 307200  (pong)
    float* BfB = AfB + 307200;       // 307200  (~5.93 MB total)

    const int NB = B_ * S_ * N_;       // 2400

    // prep: 96 pack + 16 restore + 27 WhT + 75 node0 -> A-set
    prep_kernel<<<214, 512, 0, stream>>>(x, R, pep, labels, aapos,
                                         W_e1, b_e1, t, w_t, w_b_t,
                                         W_e2, W_e2 + H_ * H_, tW_e2, W_h,
                                         we2t, WhT, xA, x0, hA, AfA, BfA);

    // ---- layer 0: reads A-set, fused node tail -> hB + B-set ----
    edge_kernel<<<NB, 256, 0, stream>>>(xA, AfA, BfA, W_e1, we2t, b_e2, W_c, b_c,
        bond, em,
        hA, WhT, b_h, W_e1 + EF_ * H_, b_e1 + H_, t, w_t + H_, w_b_t + H_, 1,
        nullptr, nullptr, 0,
        xB, hB, AfB, BfB);

    // ---- layer 1: reads B-set, fused node tail (t-layer weights) -> A-set ----
    edge_kernel<<<NB, 256, 0, stream>>>(xB, AfB, BfB, W_e1 + EF_ * H_, we2t + 16384,
        b_e2 + H_, W_c + H_, b_c + 1, bond, em,
        hB, WhT + 6720, b_h + F_, tW_e1, tb_e1, nullptr, nullptr, nullptr, 0,
        nullptr, nullptr, 0,
        xA, /*h_out dead*/ nullptr, AfA, BfA);

    // ---- t layer: reads A-set, final output fused ----
    edge_kernel<<<NB, 256, 0, stream>>>(xA, AfA, BfA, tW_e1, we2t + 32768,
        tb_e2, tW_c, tb_c, bond, em,
        nullptr, nullptr, nullptr, nullptr, nullptr, nullptr, nullptr, nullptr, 0,
        x0, amask, 1,
        out, nullptr, nullptr, nullptr);
}

// Round 7
// 289.818 us; speedup vs baseline: 1.2241x; 1.2241x over previous
//
#include <hip/hip_runtime.h>
#include <math.h>

#define B_ 2
#define S_ 8
#define N_ 150
#define H_ 128
#define F_ 40
#define EF_ 82
#define NP_ 160            // N padded to 10 j-tiles of 16
#define MPQ 136            // mbuf row pitch in bf16 elems (128 + 8 pad)

typedef __attribute__((ext_vector_type(8))) short short8;
typedef __attribute__((ext_vector_type(4))) short short4v;
typedef __attribute__((ext_vector_type(4))) float float4v;

__device__ __forceinline__ float silu_f(float v) {
    return v * __builtin_amdgcn_rcpf(1.0f + __expf(-v));
}

// fp32 -> bf16 bits, round-to-nearest-even (identical across rounds)
__device__ __forceinline__ unsigned short f2bf(float f) {
    unsigned u = __builtin_bit_cast(unsigned, f);
    return (unsigned short)((u + 0x7fffu + ((u >> 16) & 1u)) >> 16);
}

// ============ prep kernel ============
// blocks 0..95    : pack 3 layers' We2 -> bf16 transposed [c][k]
// blocks 96..111  : restore absolute coords (one bs each)
// blocks 112..138 : transpose Wh (2 layers) -> WhT[f][k] fp32
// blocks 139..213 : node0 one-hot h0 + Af/Bf via 3-row gather (4 nodes/block)
__global__ __launch_bounds__(512) void prep_kernel(
    const float* __restrict__ x, const float* __restrict__ R,
    const int* __restrict__ pep, const int* __restrict__ labels,
    const int* __restrict__ aapos,
    const float* __restrict__ We1, const float* __restrict__ be1,
    const float* __restrict__ tp, const float* __restrict__ wt,
    const float* __restrict__ wbt,
    const float* __restrict__ w2a, const float* __restrict__ w2b,
    const float* __restrict__ w2c,
    const float* __restrict__ Wh,          // [2][168][40]
    unsigned short* __restrict__ we2t,
    float* __restrict__ WhT,               // [2][40][168]
    float* __restrict__ xa, float* __restrict__ x0,
    float* __restrict__ h0, float* __restrict__ Af, float* __restrict__ Bf)
{
    int blk = blockIdx.x;
    int tid = threadIdx.x;
    if (blk < 96) {
        int e = blk * 512 + tid;                 // < 49152
        int l = e >> 14, idx = e & 16383;
        int k = idx >> 7, c = idx & 127;
        const float* src = (l == 0) ? w2a : (l == 1) ? w2b : w2c;
        we2t[l * 16384 + c * H_ + k] = f2bf(src[idx]);
    } else if (blk < 112) {
        int bs = blk - 96;
        int b = bs / S_;
        __shared__ float xL[N_ * 3];
        if (tid < N_ * 3) xL[tid] = x[bs * N_ * 3 + tid];
        __syncthreads();
        if (tid < N_ * 3) {
            int i = tid / 3, d = tid % 3;
            const float* Rrow = R + (b * N_ + i) * N_;
            float acc = 0.0f;
#pragma unroll 5
            for (int j = 0; j < N_; j++) acc += xL[j * 3 + d] * Rrow[j];
            xa[bs * N_ * 3 + tid] = acc;
            x0[bs * N_ * 3 + tid] = acc;
        }
    } else if (blk < 139) {
        int e = (blk - 112) * 512 + tid;         // < 13824
        if (e < 2 * (F_ + H_) * F_) {            // 13440
            int l = e / 6720, r = e % 6720;
            int f = r / 168, k = r % 168;
            WhT[e] = Wh[l * 6720 + k * F_ + f];
        }
    } else {
        int sub = tid >> 7, c = tid & 127;
        int bi = (blk - 139) * 4 + sub;          // < 300
        int b = bi / N_, i = bi % N_;
        int al = labels[bi];
        int ap = aapos[bi];                       // 1..15
        int aa = pep[b * 15 + ap - 1];
        int r0 = al, r1 = 5 + aa, r2 = 25 + ap - 1;
        float fa = We1[r0 * H_ + c] + We1[r1 * H_ + c] + We1[r2 * H_ + c]
                 + be1[c] + tp[b] * wt[c] + wbt[c];
        float fb = We1[(F_ + r0) * H_ + c] + We1[(F_ + r1) * H_ + c]
                 + We1[(F_ + r2) * H_ + c];
        float hv = 0.0f;
        if (c < F_) hv = (c == r0 || c == r1 || c == r2) ? 1.0f : 0.0f;
        for (int s = 0; s < S_; s++) {
            int n = (b * S_ + s) * N_ + i;
            Af[n * H_ + c] = fa;
            Bf[n * H_ + c] = fb;
            if (c < F_) h0[n * F_ + c] = hv;
        }
    }
}

// ============ edge kernel: block per (bs,i); 512 thr / 8 waves ============
// Wave w owns ONE c-tile (16 ch) -> per-thread regs ~halved vs R5/R6 (no spill).
// m-compute: thread = (row tid>>5, 4 channels (tid&31)*4).
// Loop: prefetch(jt+1) at top -> ds_read+4 MFMA -> epilogue -> m-compute(jt+1)
// -> barrier. Load-to-use window ~300cy inside one barrier interval.
// NOTE: Af_out/Bf_out MUST NOT alias Afeat/Bfeat (cross-block WAR race).
__global__ __launch_bounds__(512, 2) void edge_kernel(
    const float* __restrict__ x_in,    // [BS*N,3]
    const float* __restrict__ Afeat,   // [BS*N,128]
    const float* __restrict__ Bfeat,   // [BS*N,128]
    const float* __restrict__ We1,     // current layer [82,128]: rows 80/81
    const unsigned short* __restrict__ we2t,  // [128c][128k] bf16
    const float* __restrict__ be2,
    const float* __restrict__ Wc,
    const float* __restrict__ bcp,
    const float* __restrict__ bond,
    const float* __restrict__ emask,
    // fused node (next layer) params (unused in final mode):
    const float* __restrict__ h_in,    // [BS*N,40]
    const float* __restrict__ WhT,     // [40][168] transposed
    const float* __restrict__ bh,      // [40]
    const float* __restrict__ We1n,    // next layer [82,128]
    const float* __restrict__ be1n,
    const float* __restrict__ tpn,
    const float* __restrict__ wtn,
    const float* __restrict__ wbtn,
    int has_t_next,
    // final mode:
    const float* __restrict__ x0v,
    const float* __restrict__ amask,
    int final_mode,
    float* __restrict__ x_out,
    float* __restrict__ h_out,         // may be null (dead store elision)
    float* __restrict__ Af_out,
    float* __restrict__ Bf_out)
{
    __shared__ __align__(16) short mbuf[2][16 * MPQ];   // 8704 B
    __shared__ float4 diffE[NP_];                        // d0,d1,d2,em
    __shared__ float2 dbL[NP_];                          // dist, bond
    __shared__ float DsumL[3];
    __shared__ float wpart[8][3];
    __shared__ float cat[F_ + H_];                       // h(40) + agg(128)
    __shared__ float part[160];
    __shared__ float hnewL[F_];

    int blk = blockIdx.x;
    int i = blk % N_, bs = blk / N_, b = bs / S_;
    int tid = threadIdx.x;
    int node = bs * N_ + i;
    int lane = tid & 63, w = tid >> 6;              // 8 waves
    int qd = lane >> 4, l15 = lane & 15;
    int rowLoc = tid >> 5, cq = (tid & 31) * 4;     // m-compute mapping

    float xi0 = x_in[node * 3 + 0];
    float xi1 = x_in[node * 3 + 1];
    float xi2 = x_in[node * 3 + 2];

    // ---- stage per-j scalars ----
    if (tid < NP_) {
        int j = tid;
        float xj0 = xi0, xj1 = xi1, xj2 = xi2, bnd = 0.0f, emv = 0.0f;
        if (j < N_) {
            int nj = bs * N_ + j;
            xj0 = x_in[nj * 3 + 0];
            xj1 = x_in[nj * 3 + 1];
            xj2 = x_in[nj * 3 + 2];
            int eij = (b * N_ + i) * N_ + j;
            bnd = bond[eij];
            emv = (j == i) ? 0.0f : emask[eij];
        }
        float d0 = xi0 - xj0, d1 = xi1 - xj1, d2 = xi2 - xj2;
        diffE[j] = make_float4(d0, d1, d2, emv);
        dbL[j] = make_float2(sqrtf(d0 * d0 + d1 * d1 + d2 * d2 + 1e-12f), bnd);
    }

    // ---- hoisted m-compute constants: this thread's 4 channels ----
    float afr[4], w80r[4], w81r[4];
    {
        float4 t0 = *(const float4*)&Afeat[node * H_ + cq];
        afr[0]=t0.x; afr[1]=t0.y; afr[2]=t0.z; afr[3]=t0.w;
        t0 = *(const float4*)&We1[80 * H_ + cq];
        w80r[0]=t0.x; w80r[1]=t0.y; w80r[2]=t0.z; w80r[3]=t0.w;
        t0 = *(const float4*)&We1[81 * H_ + cq];
        w81r[0]=t0.x; w81r[1]=t0.y; w81r[2]=t0.z; w81r[3]=t0.w;
    }

    // ---- epilogue constants + hoisted We2 b-frags (1 c-tile per wave) ----
    int ccol = w * 16 + l15;
    float b2r = be2[ccol];
    float wcr = Wc[ccol];
    const unsigned short* bb = we2t + ccol * H_ + qd * 8;
    short8 bf0 = *(const short8*)(bb +  0);
    short8 bf1 = *(const short8*)(bb + 32);
    short8 bf2 = *(const short8*)(bb + 64);
    short8 bf3 = *(const short8*)(bb + 96);

    __syncthreads();

    // ---- Dsum[d] = sum_j diff (wave 0) ----
    if (w == 0) {
        float p0 = 0, p1 = 0, p2 = 0;
        for (int j = lane; j < NP_; j += 64) {
            float4 d = diffE[j];
            p0 += d.x; p1 += d.y; p2 += d.z;
        }
        for (int s = 1; s < 64; s <<= 1) {
            p0 += __shfl_xor(p0, s, 64);
            p1 += __shfl_xor(p1, s, 64);
            p2 += __shfl_xor(p2, s, 64);
        }
        if (lane == 0) { DsumL[0] = p0; DsumL[1] = p1; DsumL[2] = p2; }
    }

    // ---- prologue: compute m(tile 0) ----
    {
        float4 bv = *(const float4*)&Bfeat[(bs * N_ + rowLoc) * H_ + cq];
        float br[4] = {bv.x, bv.y, bv.z, bv.w};
        float2 db = dbL[rowLoc];
        short4v pkv;
#pragma unroll
        for (int u = 0; u < 4; u++)
            pkv[u] = (short)f2bf(silu_f(afr[u] + br[u] + db.x * w80r[u] + db.y * w81r[u]));
        *(short4v*)&mbuf[0][rowLoc * MPQ + cq] = pkv;
    }
    __syncthreads();

    float aggP = 0;
    float SP0 = 0, SP1 = 0, SP2 = 0;

#pragma unroll 1
    for (int jt = 0; jt < 10; jt++) {
        short* mb = mbuf[jt & 1];

        // TOP: issue next tile's Bfeat load (consumed at bottom of this iter)
        int jr = jt * 16 + 16 + rowLoc;
        float4 nb = {0, 0, 0, 0};
        if (jt < 9 && jr < N_)
            nb = *(const float4*)&Bfeat[(bs * N_ + jr) * H_ + cq];

        // a-frag LDS reads
        const short* arow = &mb[l15 * MPQ + qd * 8];
        short8 a0 = *(const short8*)(arow +  0);
        short8 a1 = *(const short8*)(arow + 32);
        short8 a2 = *(const short8*)(arow + 64);
        short8 a3 = *(const short8*)(arow + 96);

        // MFMA [16j x 128k] @ [128k x 16c (this wave)]
        float4v acc = {0, 0, 0, 0};
        acc = __builtin_amdgcn_mfma_f32_16x16x32_bf16(a0, bf0, acc, 0, 0, 0);
        acc = __builtin_amdgcn_mfma_f32_16x16x32_bf16(a1, bf1, acc, 0, 0, 0);
        acc = __builtin_amdgcn_mfma_f32_16x16x32_bf16(a2, bf2, acc, 0, 0, 0);
        acc = __builtin_amdgcn_mfma_f32_16x16x32_bf16(a3, bf3, acc, 0, 0, 0);

        // epilogue(jt): silu, mask, reduce over rows (load-hiding window)
#pragma unroll
        for (int r = 0; r < 4; r++) {
            int j = jt * 16 + qd * 4 + r;
            float4 de = diffE[j];
            float mv = silu_f(acc[r] + b2r) * de.w;
            aggP += mv;
            SP0 += de.x * mv; SP1 += de.y * mv; SP2 += de.z * mv;
        }

        // BOTTOM: m-compute(jt+1) — consumes the load issued at top
        if (jt < 9) {
            short4v pkv;
            if (jr < N_) {
                float br[4] = {nb.x, nb.y, nb.z, nb.w};
                float2 db = dbL[jr];
#pragma unroll
                for (int u = 0; u < 4; u++)
                    pkv[u] = (short)f2bf(silu_f(afr[u] + br[u] + db.x * w80r[u] + db.y * w81r[u]));
            } else {
                pkv[0] = 0; pkv[1] = 0; pkv[2] = 0; pkv[3] = 0;
            }
            *(short4v*)&mbuf[(jt + 1) & 1][rowLoc * MPQ + cq] = pkv;
        }
        __syncthreads();
    }

    // ---- cross-quad reduction (rows live in quads) ----
#define QR_(v) { v += __shfl_xor(v, 16, 64); v += __shfl_xor(v, 32, 64); }
    QR_(aggP)
    QR_(SP0) QR_(SP1) QR_(SP2)
#undef QR_

    // deferred cw: x_d += (sum_c Wc[c]*S[d][c] + bc*Dsum[d]) / (N-1)
    float p0 = wcr * SP0;
    float p1 = wcr * SP1;
    float p2 = wcr * SP2;
    for (int s = 1; s < 16; s <<= 1) {
        p0 += __shfl_xor(p0, s, 64);
        p1 += __shfl_xor(p1, s, 64);
        p2 += __shfl_xor(p2, s, 64);
    }
    if (lane == 0) { wpart[w][0] = p0; wpart[w][1] = p1; wpart[w][2] = p2; }
    if (!final_mode) {
        if (qd == 0) cat[F_ + ccol] = aggP;             // agg -> cat[40..167]
        if (tid < F_) cat[tid] = h_in[node * F_ + tid];
    }
    __syncthreads();
    if (tid < 3) {
        float tot = wpart[0][tid] + wpart[1][tid] + wpart[2][tid] + wpart[3][tid]
                  + wpart[4][tid] + wpart[5][tid] + wpart[6][tid] + wpart[7][tid]
                  + bcp[0] * DsumL[tid];
        float xn = x_in[node * 3 + tid] + tot * (1.0f / (float)(N_ - 1));
        if (final_mode)
            x_out[node * 3 + tid] = (xn - x0v[node * 3 + tid]) * amask[b * N_ + i];
        else
            x_out[node * 3 + tid] = xn;
    }
    if (final_mode) return;

    // ---- fused node: h_out = silu([h,agg]@Wh+bh); next-layer Af/Bf ----
    if (tid < 160) {
        int f = tid >> 2, ks = tid & 3;          // 4-way k-split of 168 = 4*42
        int k0 = ks * 42;
        const float* wr = WhT + f * (F_ + H_);
        float p = 0.0f;
#pragma unroll 6
        for (int k = k0; k < k0 + 42; k++) p += cat[k] * wr[k];
        part[tid] = p;
    }
    __syncthreads();
    if (tid < F_) {
        float hv = silu_f(part[tid * 4] + part[tid * 4 + 1] + part[tid * 4 + 2]
                        + part[tid * 4 + 3] + bh[tid]);
        hnewL[tid] = hv;
        if (h_out) h_out[node * F_ + tid] = hv;
    }
    __syncthreads();
    if (tid < 256) {
        int c = tid & 127, grp = tid >> 7;
        float acc = 0.0f;
        if (grp == 0) {
            acc = be1n[c];
            if (has_t_next) acc += tpn[b] * wtn[c] + wbtn[c];
        }
        const float* Wp = We1n + grp * F_ * H_ + c;
#pragma unroll 8
        for (int k = 0; k < F_; k++) acc += hnewL[k] * Wp[k * H_];
        if (grp == 0) Af_out[node * H_ + c] = acc;
        else          Bf_out[node * H_ + c] = acc;
    }
}

extern "C" void kernel_launch(void* const* d_in, const int* in_sizes, int n_in,
                              void* d_out, int out_size, void* d_ws, size_t ws_size,
                              hipStream_t stream) {
    const float* t     = (const float*)d_in[0];
    const float* x     = (const float*)d_in[1];
    const int*   pep   = (const int*)d_in[2];
    const int*   labels= (const int*)d_in[3];
    const int*   aapos = (const int*)d_in[4];
    const float* bond  = (const float*)d_in[5];
    const float* em    = (const float*)d_in[6];
    const float* amask = (const float*)d_in[7];
    const float* R     = (const float*)d_in[8];
    const float* W_e1  = (const float*)d_in[9];
    const float* b_e1  = (const float*)d_in[10];
    const float* W_e2  = (const float*)d_in[11];
    const float* b_e2  = (const float*)d_in[12];
    const float* W_c   = (const float*)d_in[13];
    const float* b_c   = (const float*)d_in[14];
    const float* W_h   = (const float*)d_in[15];
    const float* b_h   = (const float*)d_in[16];
    const float* w_t   = (const float*)d_in[17];
    const float* w_b_t = (const float*)d_in[18];
    const float* tW_e1 = (const float*)d_in[19];
    const float* tb_e1 = (const float*)d_in[20];
    const float* tW_e2 = (const float*)d_in[21];
    const float* tb_e2 = (const float*)d_in[22];
    const float* tW_c  = (const float*)d_in[23];
    const float* tb_c  = (const float*)d_in[24];
    float* out = (float*)d_out;

    float* ws = (float*)d_ws;
    unsigned short* we2t = (unsigned short*)ws;   // 49152 shorts = 24576 float slots
    float* WhT = ws + 24576;         // 13440  (2 layers x [40][168])
    float* x0  = WhT + 13440;        // 7200
    float* xA  = x0 + 7200;          // 7200
    float* xB  = xA + 7200;          // 7200
    float* hA  = xB + 7200;          // 96000
    float* hB  = hA + 96000;         // 96000
    float* AfA = hB + 96000;         // 307200  (ping)
    float* BfA = AfA + 307200;       // 307200
    float* AfB = BfA + 307200;       // 307200  (pong)
    float* BfB = AfB + 307200;       // 307200  (~5.93 MB total)

    const int NB = B_ * S_ * N_;       // 2400

    // prep: 96 pack + 16 restore + 27 WhT + 75 node0 -> A-set
    prep_kernel<<<214, 512, 0, stream>>>(x, R, pep, labels, aapos,
                                         W_e1, b_e1, t, w_t, w_b_t,
                                         W_e2, W_e2 + H_ * H_, tW_e2, W_h,
                                         we2t, WhT, xA, x0, hA, AfA, BfA);

    // ---- layer 0: reads A-set, fused node tail -> hB + B-set ----
    edge_kernel<<<NB, 512, 0, stream>>>(xA, AfA, BfA, W_e1, we2t, b_e2, W_c, b_c,
        bond, em,
        hA, WhT, b_h, W_e1 + EF_ * H_, b_e1 + H_, t, w_t + H_, w_b_t + H_, 1,
        nullptr, nullptr, 0,
        xB, hB, AfB, BfB);

    // ---- layer 1: reads B-set, fused node tail (t-layer weights) -> A-set ----
    edge_kernel<<<NB, 512, 0, stream>>>(xB, AfB, BfB, W_e1 + EF_ * H_, we2t + 16384,
        b_e2 + H_, W_c + H_, b_c + 1, bond, em,
        hB, WhT + 6720, b_h + F_, tW_e1, tb_e1, nullptr, nullptr, nullptr, 0,
        nullptr, nullptr, 0,
        xA, /*h_out dead*/ nullptr, AfA, BfA);

    // ---- t layer: reads A-set, final output fused ----
    edge_kernel<<<NB, 512, 0, stream>>>(xA, AfA, BfA, tW_e1, we2t + 32768,
        tb_e2, tW_c, tb_c, bond, em,
        nullptr, nullptr, nullptr, nullptr, nullptr, nullptr, nullptr, nullptr, 0,
        x0, amask, 1,
        out, nullptr, nullptr, nullptr);
}

// Round 8
// 287.801 us; speedup vs baseline: 1.2327x; 1.0070x over previous
//
#include <hip/hip_runtime.h>
#include <math.h>

#define B_ 2
#define S_ 8
#define N_ 150
#define H_ 128
#define F_ 40
#define EF_ 82
#define NP_ 160            // N padded to 10 j-tiles of 16
#define MPQ 136            // mbuf row pitch in bf16 elems (128 + 8 pad)

typedef __attribute__((ext_vector_type(8))) short short8;
typedef __attribute__((ext_vector_type(4))) float float4v;

__device__ __forceinline__ float silu_f(float v) {
    return v * __builtin_amdgcn_rcpf(1.0f + __expf(-v));
}

// fp32 -> bf16 bits, round-to-nearest-even (identical across rounds)
__device__ __forceinline__ unsigned short f2bf(float f) {
    unsigned u = __builtin_bit_cast(unsigned, f);
    return (unsigned short)((u + 0x7fffu + ((u >> 16) & 1u)) >> 16);
}

// ============ prep kernel ============
// blocks 0..95    : pack 3 layers' We2 -> bf16 transposed [c][k]
// blocks 96..111  : restore absolute coords (one bs each)
// blocks 112..138 : transpose Wh (2 layers) -> WhT[f][k] fp32
// blocks 139..213 : node0 one-hot h0 + Af/Bf via 3-row gather (4 nodes/block)
__global__ __launch_bounds__(512) void prep_kernel(
    const float* __restrict__ x, const float* __restrict__ R,
    const int* __restrict__ pep, const int* __restrict__ labels,
    const int* __restrict__ aapos,
    const float* __restrict__ We1, const float* __restrict__ be1,
    const float* __restrict__ tp, const float* __restrict__ wt,
    const float* __restrict__ wbt,
    const float* __restrict__ w2a, const float* __restrict__ w2b,
    const float* __restrict__ w2c,
    const float* __restrict__ Wh,          // [2][168][40]
    unsigned short* __restrict__ we2t,
    float* __restrict__ WhT,               // [2][40][168]
    float* __restrict__ xa, float* __restrict__ x0,
    float* __restrict__ h0, float* __restrict__ Af, float* __restrict__ Bf)
{
    int blk = blockIdx.x;
    int tid = threadIdx.x;
    if (blk < 96) {
        int e = blk * 512 + tid;                 // < 49152
        int l = e >> 14, idx = e & 16383;
        int k = idx >> 7, c = idx & 127;
        const float* src = (l == 0) ? w2a : (l == 1) ? w2b : w2c;
        we2t[l * 16384 + c * H_ + k] = f2bf(src[idx]);
    } else if (blk < 112) {
        int bs = blk - 96;
        int b = bs / S_;
        __shared__ float xL[N_ * 3];
        if (tid < N_ * 3) xL[tid] = x[bs * N_ * 3 + tid];
        __syncthreads();
        if (tid < N_ * 3) {
            int i = tid / 3, d = tid % 3;
            const float* Rrow = R + (b * N_ + i) * N_;
            float acc = 0.0f;
#pragma unroll 5
            for (int j = 0; j < N_; j++) acc += xL[j * 3 + d] * Rrow[j];
            xa[bs * N_ * 3 + tid] = acc;
            x0[bs * N_ * 3 + tid] = acc;
        }
    } else if (blk < 139) {
        int e = (blk - 112) * 512 + tid;         // < 13824
        if (e < 2 * (F_ + H_) * F_) {            // 13440
            int l = e / 6720, r = e % 6720;
            int f = r / 168, k = r % 168;
            WhT[e] = Wh[l * 6720 + k * F_ + f];
        }
    } else {
        int sub = tid >> 7, c = tid & 127;
        int bi = (blk - 139) * 4 + sub;          // < 300
        int b = bi / N_, i = bi % N_;
        int al = labels[bi];
        int ap = aapos[bi];                       // 1..15
        int aa = pep[b * 15 + ap - 1];
        int r0 = al, r1 = 5 + aa, r2 = 25 + ap - 1;
        float fa = We1[r0 * H_ + c] + We1[r1 * H_ + c] + We1[r2 * H_ + c]
                 + be1[c] + tp[b] * wt[c] + wbt[c];
        float fb = We1[(F_ + r0) * H_ + c] + We1[(F_ + r1) * H_ + c]
                 + We1[(F_ + r2) * H_ + c];
        float hv = 0.0f;
        if (c < F_) hv = (c == r0 || c == r1 || c == r2) ? 1.0f : 0.0f;
        for (int s = 0; s < S_; s++) {
            int n = (b * S_ + s) * N_ + i;
            Af[n * H_ + c] = fa;
            Bf[n * H_ + c] = fb;
            if (c < F_) h0[n * F_ + c] = hv;
        }
    }
}

// ============ edge kernel: block per (bs,i); 256 thr / 4 waves ============
// R3-style loop, 32-row intervals (two 16-row MFMA tiles per barrier).
// Thread computes rows {rowLoc, rowLoc+16}, 8 channels -> two b128 LDS writes
// (conflict-free bank pattern). Wave w owns c-tiles {2w, 2w+1}.
// 5 loop barriers. NOTE: Af_out/Bf_out must not alias Afeat/Bfeat (WAR race).
__global__ __launch_bounds__(256, 4) void edge_kernel(
    const float* __restrict__ x_in,    // [BS*N,3]
    const float* __restrict__ Afeat,   // [BS*N,128]
    const float* __restrict__ Bfeat,   // [BS*N,128]
    const float* __restrict__ We1,     // current layer [82,128]: rows 80/81
    const unsigned short* __restrict__ we2t,  // [128c][128k] bf16
    const float* __restrict__ be2,
    const float* __restrict__ Wc,
    const float* __restrict__ bcp,
    const float* __restrict__ bond,
    const float* __restrict__ emask,
    // fused node (next layer) params (unused in final mode):
    const float* __restrict__ h_in,    // [BS*N,40]
    const float* __restrict__ WhT,     // [40][168] transposed
    const float* __restrict__ bh,      // [40]
    const float* __restrict__ We1n,    // next layer [82,128]
    const float* __restrict__ be1n,
    const float* __restrict__ tpn,
    const float* __restrict__ wtn,
    const float* __restrict__ wbtn,
    int has_t_next,
    // final mode:
    const float* __restrict__ x0v,
    const float* __restrict__ amask,
    int final_mode,
    float* __restrict__ x_out,
    float* __restrict__ h_out,         // may be null (dead store elision)
    float* __restrict__ Af_out,
    float* __restrict__ Bf_out)
{
    __shared__ __align__(16) short mbuf[2][32 * MPQ];   // 17408 B
    __shared__ float4 diffE[NP_];                        // d0,d1,d2,em
    __shared__ float2 dbL[NP_];                          // dist, bond
    __shared__ float DsumL[3];
    __shared__ float wpart[4][3];
    __shared__ float cat[F_ + H_];                       // h(40) + agg(128)
    __shared__ float part[160];
    __shared__ float hnewL[F_];

    int blk = blockIdx.x;
    int i = blk % N_, bs = blk / N_, b = bs / S_;
    int tid = threadIdx.x;
    int node = bs * N_ + i;
    int lane = tid & 63, w = tid >> 6;              // 4 waves
    int qd = lane >> 4, l15 = lane & 15;
    int rowLoc = tid >> 4, c0 = (tid & 15) * 8;     // m-compute mapping

    float xi0 = x_in[node * 3 + 0];
    float xi1 = x_in[node * 3 + 1];
    float xi2 = x_in[node * 3 + 2];

    // ---- stage per-j scalars ----
    if (tid < NP_) {
        int j = tid;
        float xj0 = xi0, xj1 = xi1, xj2 = xi2, bnd = 0.0f, emv = 0.0f;
        if (j < N_) {
            int nj = bs * N_ + j;
            xj0 = x_in[nj * 3 + 0];
            xj1 = x_in[nj * 3 + 1];
            xj2 = x_in[nj * 3 + 2];
            int eij = (b * N_ + i) * N_ + j;
            bnd = bond[eij];
            emv = (j == i) ? 0.0f : emask[eij];
        }
        float d0 = xi0 - xj0, d1 = xi1 - xj1, d2 = xi2 - xj2;
        diffE[j] = make_float4(d0, d1, d2, emv);
        dbL[j] = make_float2(sqrtf(d0 * d0 + d1 * d1 + d2 * d2 + 1e-12f), bnd);
    }

    // ---- hoisted m-compute constants: this thread's 8 channels ----
    float afr[8], w80r[8], w81r[8];
    {
        float4 t0 = *(const float4*)&Afeat[node * H_ + c0];
        float4 t1 = *(const float4*)&Afeat[node * H_ + c0 + 4];
        afr[0]=t0.x; afr[1]=t0.y; afr[2]=t0.z; afr[3]=t0.w;
        afr[4]=t1.x; afr[5]=t1.y; afr[6]=t1.z; afr[7]=t1.w;
        t0 = *(const float4*)&We1[80 * H_ + c0];
        t1 = *(const float4*)&We1[80 * H_ + c0 + 4];
        w80r[0]=t0.x; w80r[1]=t0.y; w80r[2]=t0.z; w80r[3]=t0.w;
        w80r[4]=t1.x; w80r[5]=t1.y; w80r[6]=t1.z; w80r[7]=t1.w;
        t0 = *(const float4*)&We1[81 * H_ + c0];
        t1 = *(const float4*)&We1[81 * H_ + c0 + 4];
        w81r[0]=t0.x; w81r[1]=t0.y; w81r[2]=t0.z; w81r[3]=t0.w;
        w81r[4]=t1.x; w81r[5]=t1.y; w81r[6]=t1.z; w81r[7]=t1.w;
    }

    // ---- epilogue constants + hoisted We2 b-frags (2 c-tiles per wave) ----
    int ctb = w * 2;
    float b2r0 = be2[ctb * 16 + l15],  b2r1 = be2[ctb * 16 + 16 + l15];
    float wc0  = Wc[ctb * 16 + l15],   wc1  = Wc[ctb * 16 + 16 + l15];
    const unsigned short* bb0 = we2t + (ctb * 16 + l15) * H_ + qd * 8;
    const unsigned short* bb1 = bb0 + 16 * H_;
    short8 bf00 = *(const short8*)(bb0 +  0);
    short8 bf01 = *(const short8*)(bb0 + 32);
    short8 bf02 = *(const short8*)(bb0 + 64);
    short8 bf03 = *(const short8*)(bb0 + 96);
    short8 bf10 = *(const short8*)(bb1 +  0);
    short8 bf11 = *(const short8*)(bb1 + 32);
    short8 bf12 = *(const short8*)(bb1 + 64);
    short8 bf13 = *(const short8*)(bb1 + 96);

    __syncthreads();

    // ---- Dsum[d] = sum_j diff (wave 0) ----
    if (w == 0) {
        float p0 = 0, p1 = 0, p2 = 0;
        for (int j = lane; j < NP_; j += 64) {
            float4 d = diffE[j];
            p0 += d.x; p1 += d.y; p2 += d.z;
        }
        for (int s = 1; s < 64; s <<= 1) {
            p0 += __shfl_xor(p0, s, 64);
            p1 += __shfl_xor(p1, s, 64);
            p2 += __shfl_xor(p2, s, 64);
        }
        if (lane == 0) { DsumL[0] = p0; DsumL[1] = p1; DsumL[2] = p2; }
    }

    float aggP0 = 0, aggP1 = 0;
    float SP00 = 0, SP01 = 0, SP02 = 0, SP10 = 0, SP11 = 0, SP12 = 0;

#pragma unroll 1
    for (int it = 0; it < 5; it++) {
        short* mb = mbuf[it & 1];

        // ---- m-compute: rows rowLoc (tile A) and rowLoc+16 (tile B) ----
        {
            int jA = it * 32 + rowLoc;                 // always < 150
            const float* bpA = &Bfeat[(bs * N_ + jA) * H_ + c0];
            float4 a0v = *(const float4*)bpA;
            float4 a1v = *(const float4*)(bpA + 4);
            float2 dbA = dbL[jA];

            int jB = jA + 16;                          // may pad (>=150)
            float4 b0v = {0,0,0,0}, b1v = {0,0,0,0};
            float2 dbB = {0.0f, 0.0f};
            if (jB < N_) {
                const float* bpB = &Bfeat[(bs * N_ + jB) * H_ + c0];
                b0v = *(const float4*)bpB;
                b1v = *(const float4*)(bpB + 4);
                dbB = dbL[jB];
            }

            float brA[8] = {a0v.x, a0v.y, a0v.z, a0v.w, a1v.x, a1v.y, a1v.z, a1v.w};
            short8 pkA;
#pragma unroll
            for (int u = 0; u < 8; u++)
                pkA[u] = (short)f2bf(silu_f(afr[u] + brA[u] + dbA.x * w80r[u] + dbA.y * w81r[u]));
            *(short8*)&mb[rowLoc * MPQ + c0] = pkA;

            short8 pkB;
            if (jB < N_) {
                float brB[8] = {b0v.x, b0v.y, b0v.z, b0v.w, b1v.x, b1v.y, b1v.z, b1v.w};
#pragma unroll
                for (int u = 0; u < 8; u++)
                    pkB[u] = (short)f2bf(silu_f(afr[u] + brB[u] + dbB.x * w80r[u] + dbB.y * w81r[u]));
            } else {
#pragma unroll
                for (int u = 0; u < 8; u++) pkB[u] = 0;
            }
            *(short8*)&mb[(16 + rowLoc) * MPQ + c0] = pkB;
        }
        __syncthreads();

        // ---- tile A: MFMA + epilogue ----
        {
            const short* arow = &mb[l15 * MPQ + qd * 8];
            short8 a0 = *(const short8*)(arow +  0);
            short8 a1 = *(const short8*)(arow + 32);
            short8 a2 = *(const short8*)(arow + 64);
            short8 a3 = *(const short8*)(arow + 96);
            float4v acc0 = {0,0,0,0}, acc1 = {0,0,0,0};
            acc0 = __builtin_amdgcn_mfma_f32_16x16x32_bf16(a0, bf00, acc0, 0, 0, 0);
            acc1 = __builtin_amdgcn_mfma_f32_16x16x32_bf16(a0, bf10, acc1, 0, 0, 0);
            acc0 = __builtin_amdgcn_mfma_f32_16x16x32_bf16(a1, bf01, acc0, 0, 0, 0);
            acc1 = __builtin_amdgcn_mfma_f32_16x16x32_bf16(a1, bf11, acc1, 0, 0, 0);
            acc0 = __builtin_amdgcn_mfma_f32_16x16x32_bf16(a2, bf02, acc0, 0, 0, 0);
            acc1 = __builtin_amdgcn_mfma_f32_16x16x32_bf16(a2, bf12, acc1, 0, 0, 0);
            acc0 = __builtin_amdgcn_mfma_f32_16x16x32_bf16(a3, bf03, acc0, 0, 0, 0);
            acc1 = __builtin_amdgcn_mfma_f32_16x16x32_bf16(a3, bf13, acc1, 0, 0, 0);
#pragma unroll
            for (int r = 0; r < 4; r++) {
                int j = it * 32 + qd * 4 + r;
                float4 de = diffE[j];
                float mv0 = silu_f(acc0[r] + b2r0) * de.w;
                float mv1 = silu_f(acc1[r] + b2r1) * de.w;
                aggP0 += mv0; aggP1 += mv1;
                SP00 += de.x * mv0; SP01 += de.y * mv0; SP02 += de.z * mv0;
                SP10 += de.x * mv1; SP11 += de.y * mv1; SP12 += de.z * mv1;
            }
        }
        // ---- tile B: MFMA + epilogue ----
        {
            const short* arow = &mb[(16 + l15) * MPQ + qd * 8];
            short8 a0 = *(const short8*)(arow +  0);
            short8 a1 = *(const short8*)(arow + 32);
            short8 a2 = *(const short8*)(arow + 64);
            short8 a3 = *(const short8*)(arow + 96);
            float4v acc0 = {0,0,0,0}, acc1 = {0,0,0,0};
            acc0 = __builtin_amdgcn_mfma_f32_16x16x32_bf16(a0, bf00, acc0, 0, 0, 0);
            acc1 = __builtin_amdgcn_mfma_f32_16x16x32_bf16(a0, bf10, acc1, 0, 0, 0);
            acc0 = __builtin_amdgcn_mfma_f32_16x16x32_bf16(a1, bf01, acc0, 0, 0, 0);
            acc1 = __builtin_amdgcn_mfma_f32_16x16x32_bf16(a1, bf11, acc1, 0, 0, 0);
            acc0 = __builtin_amdgcn_mfma_f32_16x16x32_bf16(a2, bf02, acc0, 0, 0, 0);
            acc1 = __builtin_amdgcn_mfma_f32_16x16x32_bf16(a2, bf12, acc1, 0, 0, 0);
            acc0 = __builtin_amdgcn_mfma_f32_16x16x32_bf16(a3, bf03, acc0, 0, 0, 0);
            acc1 = __builtin_amdgcn_mfma_f32_16x16x32_bf16(a3, bf13, acc1, 0, 0, 0);
#pragma unroll
            for (int r = 0; r < 4; r++) {
                int j = it * 32 + 16 + qd * 4 + r;
                float4 de = diffE[j];
                float mv0 = silu_f(acc0[r] + b2r0) * de.w;
                float mv1 = silu_f(acc1[r] + b2r1) * de.w;
                aggP0 += mv0; aggP1 += mv1;
                SP00 += de.x * mv0; SP01 += de.y * mv0; SP02 += de.z * mv0;
                SP10 += de.x * mv1; SP11 += de.y * mv1; SP12 += de.z * mv1;
            }
        }
    }

    // ---- cross-quad reduction (rows live in quads) ----
#define QR_(v) { v += __shfl_xor(v, 16, 64); v += __shfl_xor(v, 32, 64); }
    QR_(aggP0) QR_(aggP1)
    QR_(SP00) QR_(SP01) QR_(SP02)
    QR_(SP10) QR_(SP11) QR_(SP12)
#undef QR_

    // deferred cw: x_d += (sum_c Wc[c]*S[d][c] + bc*Dsum[d]) / (N-1)
    float p0 = wc0 * SP00 + wc1 * SP10;
    float p1 = wc0 * SP01 + wc1 * SP11;
    float p2 = wc0 * SP02 + wc1 * SP12;
    for (int s = 1; s < 16; s <<= 1) {
        p0 += __shfl_xor(p0, s, 64);
        p1 += __shfl_xor(p1, s, 64);
        p2 += __shfl_xor(p2, s, 64);
    }
    if (lane == 0) { wpart[w][0] = p0; wpart[w][1] = p1; wpart[w][2] = p2; }
    if (!final_mode) {
        if (qd == 0) {
            cat[F_ + ctb * 16 + l15]      = aggP0;      // agg -> cat[40..167]
            cat[F_ + ctb * 16 + 16 + l15] = aggP1;
        }
        if (tid < F_) cat[tid] = h_in[node * F_ + tid];
    }
    __syncthreads();
    if (tid < 3) {
        float tot = wpart[0][tid] + wpart[1][tid] + wpart[2][tid] + wpart[3][tid]
                  + bcp[0] * DsumL[tid];
        float xn = x_in[node * 3 + tid] + tot * (1.0f / (float)(N_ - 1));
        if (final_mode)
            x_out[node * 3 + tid] = (xn - x0v[node * 3 + tid]) * amask[b * N_ + i];
        else
            x_out[node * 3 + tid] = xn;
    }
    if (final_mode) return;

    // ---- fused node: h_out = silu([h,agg]@Wh+bh); next-layer Af/Bf ----
    if (tid < 160) {
        int f = tid >> 2, ks = tid & 3;          // 4-way k-split of 168 = 4*42
        int k0 = ks * 42;
        const float* wr = WhT + f * (F_ + H_);
        float p = 0.0f;
#pragma unroll 6
        for (int k = k0; k < k0 + 42; k++) p += cat[k] * wr[k];
        part[tid] = p;
    }
    __syncthreads();
    if (tid < F_) {
        float hv = silu_f(part[tid * 4] + part[tid * 4 + 1] + part[tid * 4 + 2]
                        + part[tid * 4 + 3] + bh[tid]);
        hnewL[tid] = hv;
        if (h_out) h_out[node * F_ + tid] = hv;
    }
    __syncthreads();
    {
        int c = tid & 127, grp = tid >> 7;
        float acc = 0.0f;
        if (grp == 0) {
            acc = be1n[c];
            if (has_t_next) acc += tpn[b] * wtn[c] + wbtn[c];
        }
        const float* Wp = We1n + grp * F_ * H_ + c;
#pragma unroll 8
        for (int k = 0; k < F_; k++) acc += hnewL[k] * Wp[k * H_];
        if (grp == 0) Af_out[node * H_ + c] = acc;
        else          Bf_out[node * H_ + c] = acc;
    }
}

extern "C" void kernel_launch(void* const* d_in, const int* in_sizes, int n_in,
                              void* d_out, int out_size, void* d_ws, size_t ws_size,
                              hipStream_t stream) {
    const float* t     = (const float*)d_in[0];
    const float* x     = (const float*)d_in[1];
    const int*   pep   = (const int*)d_in[2];
    const int*   labels= (const int*)d_in[3];
    const int*   aapos = (const int*)d_in[4];
    const float* bond  = (const float*)d_in[5];
    const float* em    = (const float*)d_in[6];
    const float* amask = (const float*)d_in[7];
    const float* R     = (const float*)d_in[8];
    const float* W_e1  = (const float*)d_in[9];
    const float* b_e1  = (const float*)d_in[10];
    const float* W_e2  = (const float*)d_in[11];
    const float* b_e2  = (const float*)d_in[12];
    const float* W_c   = (const float*)d_in[13];
    const float* b_c   = (const float*)d_in[14];
    const float* W_h   = (const float*)d_in[15];
    const float* b_h   = (const float*)d_in[16];
    const float* w_t   = (const float*)d_in[17];
    const float* w_b_t = (const float*)d_in[18];
    const float* tW_e1 = (const float*)d_in[19];
    const float* tb_e1 = (const float*)d_in[20];
    const float* tW_e2 = (const float*)d_in[21];
    const float* tb_e2 = (const float*)d_in[22];
    const float* tW_c  = (const float*)d_in[23];
    const float* tb_c  = (const float*)d_in[24];
    float* out = (float*)d_out;

    float* ws = (float*)d_ws;
    unsigned short* we2t = (unsigned short*)ws;   // 49152 shorts = 24576 float slots
    float* WhT = ws + 24576;         // 13440  (2 layers x [40][168])
    float* x0  = WhT + 13440;        // 7200
    float* xA  = x0 + 7200;          // 7200
    float* xB  = xA + 7200;          // 7200
    float* hA  = xB + 7200;          // 96000
    float* hB  = hA + 96000;         // 96000
    float* AfA = hB + 96000;         // 307200  (ping)
    float* BfA = AfA + 307200;       // 307200
    float* AfB = BfA + 307200;       // 307200  (pong)
    float* BfB = AfB + 307200;       // 307200  (~5.93 MB total)

    const int NB = B_ * S_ * N_;       // 2400

    // prep: 96 pack + 16 restore + 27 WhT + 75 node0 -> A-set
    prep_kernel<<<214, 512, 0, stream>>>(x, R, pep, labels, aapos,
                                         W_e1, b_e1, t, w_t, w_b_t,
                                         W_e2, W_e2 + H_ * H_, tW_e2, W_h,
                                         we2t, WhT, xA, x0, hA, AfA, BfA);

    // ---- layer 0: reads A-set, fused node tail -> hB + B-set ----
    edge_kernel<<<NB, 256, 0, stream>>>(xA, AfA, BfA, W_e1, we2t, b_e2, W_c, b_c,
        bond, em,
        hA, WhT, b_h, W_e1 + EF_ * H_, b_e1 + H_, t, w_t + H_, w_b_t + H_, 1,
        nullptr, nullptr, 0,
        xB, hB, AfB, BfB);

    // ---- layer 1: reads B-set, fused node tail (t-layer weights) -> A-set ----
    edge_kernel<<<NB, 256, 0, stream>>>(xB, AfB, BfB, W_e1 + EF_ * H_, we2t + 16384,
        b_e2 + H_, W_c + H_, b_c + 1, bond, em,
        hB, WhT + 6720, b_h + F_, tW_e1, tb_e1, nullptr, nullptr, nullptr, 0,
        nullptr, nullptr, 0,
        xA, /*h_out dead*/ nullptr, AfA, BfA);

    // ---- t layer: reads A-set, final output fused ----
    edge_kernel<<<NB, 256, 0, stream>>>(xA, AfA, BfA, tW_e1, we2t + 32768,
        tb_e2, tW_c, tb_c, bond, em,
        nullptr, nullptr, nullptr, nullptr, nullptr, nullptr, nullptr, nullptr, 0,
        x0, amask, 1,
        out, nullptr, nullptr, nullptr);
}